// Round 6
// baseline (273.629 us; speedup 1.0000x reference)
//
#include <hip/hip_runtime.h>
#include <hip/hip_bf16.h>
#include <stdint.h>

typedef __attribute__((ext_vector_type(8)))  __bf16   bf16x8;
typedef __attribute__((ext_vector_type(4)))  float    f32x4;
typedef __attribute__((ext_vector_type(16))) float    f32x16;
typedef __attribute__((ext_vector_type(4)))  unsigned u32x4;
typedef __attribute__((ext_vector_type(2)))  unsigned u32x2;

#define BATCH  2
#define SEQ    2048
#define DMODEL 1024
#define NHEAD  16
#define HDIM   64
#define MTOT   (BATCH * SEQ)   // 4096
#define MOFF   8.0f            // fixed softmax offset (exp2 domain)

// async global->LDS, 16B per lane (dest = wave-uniform base + lane*16)
__device__ __forceinline__ void gload_lds16(const void* g, void* l) {
  __builtin_amdgcn_global_load_lds(
      (const __attribute__((address_space(1))) unsigned int*)g,
      (__attribute__((address_space(3))) unsigned int*)(uintptr_t)l,
      16, 0, 0);
}

// pack two f32 -> one dword of 2 bf16 (compiler emits v_cvt_pk_bf16_f32)
__device__ __forceinline__ unsigned pkbf(float a, float b) {
  unsigned lo = (unsigned)__builtin_bit_cast(unsigned short, (__bf16)a);
  unsigned hb = (unsigned)__builtin_bit_cast(unsigned short, (__bf16)b);
  return lo | (hb << 16);
}

// ---------- fused fp32 -> bf16 casts (all 5 tensors, one launch) ----------
__global__ void cast_all(const float* __restrict__ x,  const float* __restrict__ wq,
                         const float* __restrict__ wk, const float* __restrict__ wv,
                         const float* __restrict__ wo,
                         __bf16* __restrict__ xb,  __bf16* __restrict__ wqb,
                         __bf16* __restrict__ wkb, __bf16* __restrict__ wvb,
                         __bf16* __restrict__ wob)
{
  const float* in; __bf16* out; int n;
  switch (blockIdx.y) {
    case 0:  in = x;  out = xb;  n = MTOT * DMODEL;   break;
    case 1:  in = wq; out = wqb; n = DMODEL * DMODEL; break;
    case 2:  in = wk; out = wkb; n = DMODEL * DMODEL; break;
    case 3:  in = wv; out = wvb; n = DMODEL * DMODEL; break;
    default: in = wo; out = wob; n = DMODEL * DMODEL; break;
  }
  const int i = blockIdx.x * blockDim.x + threadIdx.x;
  const int stride = gridDim.x * blockDim.x;
  for (int idx = i; idx * 8 < n; idx += stride) {
    const float4 a = ((const float4*)in)[idx * 2];
    const float4 b = ((const float4*)in)[idx * 2 + 1];
    bf16x8 v = { (__bf16)a.x, (__bf16)a.y, (__bf16)a.z, (__bf16)a.w,
                 (__bf16)b.x, (__bf16)b.y, (__bf16)b.z, (__bf16)b.w };
    *(bf16x8*)(out + (size_t)idx * 8) = v;
  }
}

// ---------- shared 128x128 GEMM mainloop: acc = A[128,K] * W[128,K]^T ----------
__device__ __forceinline__ void gemm_tile_128(const __bf16* __restrict__ A,
                                              const __bf16* __restrict__ W,
                                              int bm, int bn, int Kd,
                                              f32x4 (&acc)[4][4])
{
  __shared__ __align__(16) __bf16 As[128 * 32];
  __shared__ __align__(16) __bf16 Bs[128 * 32];
  const int tid  = threadIdx.x;
  const int wave = tid >> 6, lane = tid & 63;
  const int wr = wave >> 1, wc = wave & 1;
  const int fr = lane & 15, fq = lane >> 4;
  const int c0 = tid, c1 = tid + 256;
  const __bf16* gA0 = A + (size_t)(bm * 128 + (c0 >> 2)) * Kd + (c0 & 3) * 8;
  const __bf16* gA1 = A + (size_t)(bm * 128 + (c1 >> 2)) * Kd + (c1 & 3) * 8;
  const __bf16* gB0 = W + (size_t)(bn * 128 + (c0 >> 2)) * Kd + (c0 & 3) * 8;
  const __bf16* gB1 = W + (size_t)(bn * 128 + (c1 >> 2)) * Kd + (c1 & 3) * 8;

  for (int k0 = 0; k0 < Kd; k0 += 32) {
    gload_lds16(gA0 + k0, As + c0 * 8);
    gload_lds16(gB0 + k0, Bs + c0 * 8);
    gload_lds16(gA1 + k0, As + c1 * 8);
    gload_lds16(gB1 + k0, Bs + c1 * 8);
    __syncthreads();
    bf16x8 a[4], b[4];
#pragma unroll
    for (int m = 0; m < 4; ++m)
      a[m] = *(const bf16x8*)(As + (wr * 64 + m * 16 + fr) * 32 + fq * 8);
#pragma unroll
    for (int n = 0; n < 4; ++n)
      b[n] = *(const bf16x8*)(Bs + (wc * 64 + n * 16 + fr) * 32 + fq * 8);
#pragma unroll
    for (int m = 0; m < 4; ++m)
#pragma unroll
      for (int n = 0; n < 4; ++n)
        acc[m][n] = __builtin_amdgcn_mfma_f32_16x16x32_bf16(a[m], b[n], acc[m][n], 0, 0, 0);
    __syncthreads();
  }
}

// ---------- QKV projections (z=0: Q*scale, z=1: K, z=2: VT = Wv * x^T) ----------
__global__ __launch_bounds__(256)
void gemm_qkv(const __bf16* __restrict__ xb,
              const __bf16* __restrict__ Wq, const __bf16* __restrict__ Wk,
              const __bf16* __restrict__ Wv,
              __bf16* __restrict__ Qo, __bf16* __restrict__ Ko, __bf16* __restrict__ VTo,
              float qscale)
{
  const int z = blockIdx.z;
  const __bf16* A; const __bf16* W; __bf16* Ob; float scale; int bm, bn, Nn;
  if (z == 2)      { A = Wv; W = xb; Ob = VTo; scale = 1.f;    bm = blockIdx.y; bn = blockIdx.x; Nn = MTOT;   }
  else if (z == 1) { A = xb; W = Wk; Ob = Ko;  scale = 1.f;    bm = blockIdx.x; bn = blockIdx.y; Nn = DMODEL; }
  else             { A = xb; W = Wq; Ob = Qo;  scale = qscale; bm = blockIdx.x; bn = blockIdx.y; Nn = DMODEL; }

  f32x4 acc[4][4] = {};
  gemm_tile_128(A, W, bm, bn, DMODEL, acc);

  const int lane = threadIdx.x & 63, wave = threadIdx.x >> 6;
  const int wr = wave >> 1, wc = wave & 1;
  const int fr = lane & 15, fq = lane >> 4;
#pragma unroll
  for (int m = 0; m < 4; ++m)
#pragma unroll
    for (int n = 0; n < 4; ++n) {
      const int col = bn * 128 + wc * 64 + n * 16 + fr;
#pragma unroll
      for (int j = 0; j < 4; ++j) {
        const int row = bm * 128 + wr * 64 + m * 16 + fq * 4 + j;
        Ob[(size_t)row * Nn + col] = (__bf16)(acc[m][n][j] * scale);
      }
    }
}

// ---------- output projection: out = ctx * Wo^T + b ----------
__global__ __launch_bounds__(256)
void gemm_out(const __bf16* __restrict__ A, const __bf16* __restrict__ W,
              float* __restrict__ OF, const float* __restrict__ bias)
{
  f32x4 acc[4][4] = {};
  gemm_tile_128(A, W, blockIdx.x, blockIdx.y, DMODEL, acc);

  const int lane = threadIdx.x & 63, wave = threadIdx.x >> 6;
  const int wr = wave >> 1, wc = wave & 1;
  const int fr = lane & 15, fq = lane >> 4;
#pragma unroll
  for (int m = 0; m < 4; ++m)
#pragma unroll
    for (int n = 0; n < 4; ++n) {
      const int col = blockIdx.y * 128 + wc * 64 + n * 16 + fr;
#pragma unroll
      for (int j = 0; j < 4; ++j) {
        const int row = blockIdx.x * 128 + wr * 64 + m * 16 + fq * 4 + j;
        OF[(size_t)row * DMODEL + col] = acc[m][n][j] + bias[col];
      }
    }
}

// ---------- flash attention ----------
// WG = 256 thr = 4 waves. All waves own q-tile pair (jp, 63-jp); kv tiles
// split 4-way by wave parity -> per-wave step counts differ by <=1.
// Fixed softmax offset (no max tracking): P = exp2(S - 8); offset cancels in
// the final normalization, so parity partials combine by pure addition via a
// 36KB LDS buffer (staged: L then H) + 3 barriers. 1024 WGs -> 4096 waves =
// 4/SIMD, each with 2 independent streams = 8 chains/SIMD.
// Swapped QK^T via 32x32x16 MFMA: S^T[kv][q], q = lane&31.
// C/D layout (m74/m101): col=lane&31, row=(r&3)+8*(r>>2)+4*(lane>>5).

__device__ __forceinline__ void mask_tile(f32x16& sv0, f32x16& sv1,
                                          int kv0, int q0, int ln, int hi)
{
  const int qg = q0 + ln;
#pragma unroll
  for (int r = 0; r < 16; ++r) {
    const int kvo = kv0 + (r & 3) + 8 * (r >> 2) + 4 * hi;
    if (kvo > qg)      sv0[r] = -1e30f;
    if (kvo + 32 > qg) sv1[r] = -1e30f;
  }
}

// exp2(S - MOFF), lane-local l accumulate, pack P, PV accumulate
__device__ __forceinline__ void stream_fin(f32x16& sv0, f32x16& sv1, float& l_acc,
                                           f32x16& c0, f32x16& c1,
                                           const bf16x8 (&vt0)[4], const bf16x8 (&vt1)[4],
                                           int hi)
{
#pragma unroll
  for (int r = 0; r < 16; ++r) {
    sv0[r] = __builtin_amdgcn_exp2f(sv0[r] - MOFF);
    sv1[r] = __builtin_amdgcn_exp2f(sv1[r] - MOFF);
  }
  // lane-local partial sum (cross-lane combine deferred to epilogue)
  float s8[8];
#pragma unroll
  for (int r = 0; r < 8; ++r)
    s8[r] = (sv0[r] + sv0[r + 8]) + (sv1[r] + sv1[r + 8]);
#pragma unroll
  for (int r = 0; r < 4; ++r) s8[r] += s8[r + 4];
  l_acc += (s8[0] + s8[1]) + (s8[2] + s8[3]);

  // pack P into PV B-fragments (half-exchange via shfl_xor 32)
  bf16x8 pf[4];
#pragma unroll
  for (int half = 0; half < 2; ++half) {
    const int r0 = half * 8;
    {
      unsigned pk01 = pkbf(sv0[r0 + 0], sv0[r0 + 1]);
      unsigned pk23 = pkbf(sv0[r0 + 2], sv0[r0 + 3]);
      unsigned pk45 = pkbf(sv0[r0 + 4], sv0[r0 + 5]);
      unsigned pk67 = pkbf(sv0[r0 + 6], sv0[r0 + 7]);
      unsigned x01 = (unsigned)__shfl_xor((int)pk01, 32, 64);
      unsigned x23 = (unsigned)__shfl_xor((int)pk23, 32, 64);
      unsigned x45 = (unsigned)__shfl_xor((int)pk45, 32, 64);
      unsigned x67 = (unsigned)__shfl_xor((int)pk67, 32, 64);
      u32x4 uw = { hi ? x45 : pk01, hi ? x67 : pk23,
                   hi ? pk45 : x01, hi ? pk67 : x23 };
      pf[half] = __builtin_bit_cast(bf16x8, uw);
    }
    {
      unsigned pk01 = pkbf(sv1[r0 + 0], sv1[r0 + 1]);
      unsigned pk23 = pkbf(sv1[r0 + 2], sv1[r0 + 3]);
      unsigned pk45 = pkbf(sv1[r0 + 4], sv1[r0 + 5]);
      unsigned pk67 = pkbf(sv1[r0 + 6], sv1[r0 + 7]);
      unsigned x01 = (unsigned)__shfl_xor((int)pk01, 32, 64);
      unsigned x23 = (unsigned)__shfl_xor((int)pk23, 32, 64);
      unsigned x45 = (unsigned)__shfl_xor((int)pk45, 32, 64);
      unsigned x67 = (unsigned)__shfl_xor((int)pk67, 32, 64);
      u32x4 uw = { hi ? x45 : pk01, hi ? x67 : pk23,
                   hi ? pk45 : x01, hi ? pk67 : x23 };
      pf[2 + half] = __builtin_bit_cast(bf16x8, uw);
    }
  }

  // PV: ctx^T[d][q] += V^T-frag * P-frag
  __builtin_amdgcn_s_setprio(1);
#pragma unroll
  for (int kc = 0; kc < 4; ++kc)
    c0 = __builtin_amdgcn_mfma_f32_32x32x16_bf16(vt0[kc], pf[kc], c0, 0, 0, 0);
#pragma unroll
  for (int kc = 0; kc < 4; ++kc)
    c1 = __builtin_amdgcn_mfma_f32_32x32x16_bf16(vt1[kc], pf[kc], c1, 0, 0, 0);
  __builtin_amdgcn_s_setprio(0);
}

__global__ __launch_bounds__(256, 4)
void attn_kernel(const __bf16* __restrict__ Qg, const __bf16* __restrict__ Kg,
                 const __bf16* __restrict__ VTg, __bf16* __restrict__ Og)
{
  __shared__ __align__(16) float Cs[4][32][68];   // [parity][q][d+pad] ~34.8 KB
  __shared__ float Ls[4][2][32];                  // [parity][hi][q]

  const int tid  = threadIdx.x;
  const int p    = tid >> 6;          // wave id = kv parity (0..3)
  const int lane = tid & 63;
  const int ln = lane & 31, hi = lane >> 5;
  const int bI = blockIdx.x;          // 0..1023
  const int bh = bI & 31;             // bh%8 == blockIdx%8 -> XCD L2 locality
  const int jp = bI >> 5;             // 0..31 -> q-tile pair (jp, 63-jp)
  const int b = bh >> 4, h = bh & 15;

  const int qtL = jp, qtH = 63 - jp;
  const int q0L = qtL * 32, q0H = qtH * 32;
  const int ntL = (qtL >> 1) + 1, ntH = (qtH >> 1) + 1;   // ntL <= ntH, ntH >= 17

  const __bf16* Kp  = Kg  + (size_t)b * SEQ * DMODEL + h * HDIM + hi * 8;
  const __bf16* Vp  = VTg + (size_t)(h * HDIM) * MTOT + (size_t)b * SEQ + hi * 8;
  const __bf16* QpL = Qg + ((size_t)b * SEQ + q0L + ln) * DMODEL + h * HDIM + hi * 8;
  const __bf16* QpH = Qg + ((size_t)b * SEQ + q0H + ln) * DMODEL + h * HDIM + hi * 8;

  // Q fragments (B-operand): q=ln, k = kc*16 + hi*8 + j  (Q pre-scaled 0.125*log2e)
  bf16x8 qfL[4], qfH[4];
#pragma unroll
  for (int kc = 0; kc < 4; ++kc) {
    qfL[kc] = *(const bf16x8*)(QpL + kc * 16);
    qfH[kc] = *(const bf16x8*)(QpH + kc * 16);
  }

  f32x16 cL0 = {}, cL1 = {}, cH0 = {}, cH1 = {};
  float lL = 0.f, lH = 0.f;

  for (int t = p; t < ntH; t += 4) {
    const int kv0 = t * 64;

    // K fragments (A-operand) first, then V^T: QK^T only waits on K
    bf16x8 kA[4], kB[4], vt0[4], vt1[4];
#pragma unroll
    for (int kc = 0; kc < 4; ++kc) {
      kA[kc]  = *(const bf16x8*)(Kp + (size_t)(kv0 + ln) * DMODEL + kc * 16);
      kB[kc]  = *(const bf16x8*)(Kp + (size_t)(kv0 + 32 + ln) * DMODEL + kc * 16);
    }
#pragma unroll
    for (int kc = 0; kc < 4; ++kc) {
      vt0[kc] = *(const bf16x8*)(Vp + (size_t)ln * MTOT + kv0 + kc * 16);
      vt1[kc] = *(const bf16x8*)(Vp + (size_t)(32 + ln) * MTOT + kv0 + kc * 16);
    }

    // ---- H stream (always active) ----
    {
      f32x16 s0 = {}, s1 = {};
      __builtin_amdgcn_s_setprio(1);
#pragma unroll
      for (int kc = 0; kc < 4; ++kc) {
        s0 = __builtin_amdgcn_mfma_f32_32x32x16_bf16(kA[kc], qfH[kc], s0, 0, 0, 0);
        s1 = __builtin_amdgcn_mfma_f32_32x32x16_bf16(kB[kc], qfH[kc], s1, 0, 0, 0);
      }
      __builtin_amdgcn_s_setprio(0);
      if (t == ntH - 1) mask_tile(s0, s1, kv0, q0H, ln, hi);
      stream_fin(s0, s1, lH, cH0, cH1, vt0, vt1, hi);
    }

    // ---- L stream (while active) ----
    if (t < ntL) {
      f32x16 s0 = {}, s1 = {};
      __builtin_amdgcn_s_setprio(1);
#pragma unroll
      for (int kc = 0; kc < 4; ++kc) {
        s0 = __builtin_amdgcn_mfma_f32_32x32x16_bf16(kA[kc], qfL[kc], s0, 0, 0, 0);
        s1 = __builtin_amdgcn_mfma_f32_32x32x16_bf16(kB[kc], qfL[kc], s1, 0, 0, 0);
      }
      __builtin_amdgcn_s_setprio(0);
      if (t == ntL - 1) mask_tile(s0, s1, kv0, q0L, ln, hi);
      stream_fin(s0, s1, lL, cL0, cL1, vt0, vt1, hi);
    }
  }

  // ---- staged 4-way combine (offset-softmax partials add exactly) ----
  // epilogue lane mapping: wave p handles q rows [p*8, p*8+8)
  const int qe = (p << 3) | (lane >> 3);
  const int de = (lane & 7) * 8;

  // Stage 1: everyone exports L partials
#pragma unroll
  for (int g = 0; g < 4; ++g) {
    f32x4 v0 = { cL0[4*g+0], cL0[4*g+1], cL0[4*g+2], cL0[4*g+3] };
    f32x4 v1 = { cL1[4*g+0], cL1[4*g+1], cL1[4*g+2], cL1[4*g+3] };
    *(f32x4*)&Cs[p][ln][g * 8 + hi * 4]      = v0;
    *(f32x4*)&Cs[p][ln][32 + g * 8 + hi * 4] = v1;
  }
  Ls[p][hi][ln] = lL;
  __syncthreads();

  // Stage 2: every wave reduces 8 q-rows of L and writes out
  {
    float lt = 0.f;
#pragma unroll
    for (int pp = 0; pp < 4; ++pp) lt += Ls[pp][0][qe] + Ls[pp][1][qe];
    const float inv = 1.0f / lt;
    f32x4 a0 = {}, a1 = {};
#pragma unroll
    for (int pp = 0; pp < 4; ++pp) {
      a0 += *(const f32x4*)&Cs[pp][qe][de];
      a1 += *(const f32x4*)&Cs[pp][qe][de + 4];
    }
    u32x4 w = { pkbf(a0[0] * inv, a0[1] * inv), pkbf(a0[2] * inv, a0[3] * inv),
                pkbf(a1[0] * inv, a1[1] * inv), pkbf(a1[2] * inv, a1[3] * inv) };
    *(u32x4*)(Og + ((size_t)b * SEQ + q0L + qe) * DMODEL + h * HDIM + de) = w;
  }
  __syncthreads();   // everyone done reading L before overwriting with H

  // Stage 3: everyone exports H partials
#pragma unroll
  for (int g = 0; g < 4; ++g) {
    f32x4 v0 = { cH0[4*g+0], cH0[4*g+1], cH0[4*g+2], cH0[4*g+3] };
    f32x4 v1 = { cH1[4*g+0], cH1[4*g+1], cH1[4*g+2], cH1[4*g+3] };
    *(f32x4*)&Cs[p][ln][g * 8 + hi * 4]      = v0;
    *(f32x4*)&Cs[p][ln][32 + g * 8 + hi * 4] = v1;
  }
  Ls[p][hi][ln] = lH;
  __syncthreads();

  // Stage 4: every wave reduces 8 q-rows of H and writes out
  {
    float lt = 0.f;
#pragma unroll
    for (int pp = 0; pp < 4; ++pp) lt += Ls[pp][0][qe] + Ls[pp][1][qe];
    const float inv = 1.0f / lt;
    f32x4 a0 = {}, a1 = {};
#pragma unroll
    for (int pp = 0; pp < 4; ++pp) {
      a0 += *(const f32x4*)&Cs[pp][qe][de];
      a1 += *(const f32x4*)&Cs[pp][qe][de + 4];
    }
    u32x4 w = { pkbf(a0[0] * inv, a0[1] * inv), pkbf(a0[2] * inv, a0[3] * inv),
                pkbf(a1[0] * inv, a1[1] * inv), pkbf(a1[2] * inv, a1[3] * inv) };
    *(u32x4*)(Og + ((size_t)b * SEQ + q0H + qe) * DMODEL + h * HDIM + de) = w;
  }
}

// ---------- launch ----------
extern "C" void kernel_launch(void* const* d_in, const int* in_sizes, int n_in,
                              void* d_out, int out_size, void* d_ws, size_t ws_size,
                              hipStream_t stream) {
  (void)in_sizes; (void)n_in; (void)out_size; (void)ws_size;
  const float* x  = (const float*)d_in[0];
  const float* Wq = (const float*)d_in[1];
  const float* Wk = (const float*)d_in[2];
  const float* Wv = (const float*)d_in[3];
  const float* Wo = (const float*)d_in[4];
  const float* bo = (const float*)d_in[5];
  float* out = (float*)d_out;

  __bf16* ws  = (__bf16*)d_ws;
  __bf16* xb  = ws;                                   // 4M elems
  __bf16* Wqb = xb  + (size_t)MTOT * DMODEL;
  __bf16* Wkb = Wqb + (size_t)DMODEL * DMODEL;
  __bf16* Wvb = Wkb + (size_t)DMODEL * DMODEL;
  __bf16* Wob = Wvb + (size_t)DMODEL * DMODEL;
  __bf16* Qb  = Wob + (size_t)DMODEL * DMODEL;        // 4M
  __bf16* Kb  = Qb  + (size_t)MTOT * DMODEL;          // 4M
  __bf16* VTb = Kb  + (size_t)MTOT * DMODEL;          // 4M, layout [1024][4096]
  __bf16* ctxb = xb;  // reuse: x is dead after QKV projections

  cast_all<<<dim3(256, 5), 256, 0, stream>>>(x, Wq, Wk, Wv, Wo,
                                             xb, Wqb, Wkb, Wvb, Wob);

  // scale = 1/sqrt(64) * log2(e), folded into Q so softmax uses exp2
  const float qscale = 0.125f * 1.4426950408889634f;
  gemm_qkv<<<dim3(32, 8, 3), 256, 0, stream>>>(xb, Wqb, Wkb, Wvb, Qb, Kb, VTb, qscale);

  attn_kernel<<<dim3(1024), 256, 0, stream>>>(Qb, Kb, VTb, ctxb);

  gemm_out<<<dim3(32, 8), 256, 0, stream>>>(ctxb, Wob, out, bo);
}

// Round 7
// 100.075 us; speedup vs baseline: 2.7342x; 2.7342x over previous
//
#include <hip/hip_runtime.h>
#include <hip/hip_bf16.h>
#include <stdint.h>

typedef __attribute__((ext_vector_type(8)))  __bf16   bf16x8;
typedef __attribute__((ext_vector_type(4)))  float    f32x4;
typedef __attribute__((ext_vector_type(16))) float    f32x16;
typedef __attribute__((ext_vector_type(4)))  unsigned u32x4;
typedef __attribute__((ext_vector_type(2)))  unsigned u32x2;

#define BATCH  2
#define SEQ    2048
#define DMODEL 1024
#define NHEAD  16
#define HDIM   64
#define MTOT   (BATCH * SEQ)   // 4096
#define MOFF   8.0f            // fixed softmax offset (exp2 domain)

// async global->LDS, 16B per lane (dest = wave-uniform base + lane*16)
__device__ __forceinline__ void gload_lds16(const void* g, void* l) {
  __builtin_amdgcn_global_load_lds(
      (const __attribute__((address_space(1))) unsigned int*)g,
      (__attribute__((address_space(3))) unsigned int*)(uintptr_t)l,
      16, 0, 0);
}

// pack two f32 -> one dword of 2 bf16 (compiler emits v_cvt_pk_bf16_f32)
__device__ __forceinline__ unsigned pkbf(float a, float b) {
  unsigned lo = (unsigned)__builtin_bit_cast(unsigned short, (__bf16)a);
  unsigned hb = (unsigned)__builtin_bit_cast(unsigned short, (__bf16)b);
  return lo | (hb << 16);
}

// ---------- fused fp32 -> bf16 casts (all 5 tensors, one launch) ----------
__global__ void cast_all(const float* __restrict__ x,  const float* __restrict__ wq,
                         const float* __restrict__ wk, const float* __restrict__ wv,
                         const float* __restrict__ wo,
                         __bf16* __restrict__ xb,  __bf16* __restrict__ wqb,
                         __bf16* __restrict__ wkb, __bf16* __restrict__ wvb,
                         __bf16* __restrict__ wob)
{
  const float* in; __bf16* out; int n;
  switch (blockIdx.y) {
    case 0:  in = x;  out = xb;  n = MTOT * DMODEL;   break;
    case 1:  in = wq; out = wqb; n = DMODEL * DMODEL; break;
    case 2:  in = wk; out = wkb; n = DMODEL * DMODEL; break;
    case 3:  in = wv; out = wvb; n = DMODEL * DMODEL; break;
    default: in = wo; out = wob; n = DMODEL * DMODEL; break;
  }
  const int i = blockIdx.x * blockDim.x + threadIdx.x;
  const int stride = gridDim.x * blockDim.x;
  for (int idx = i; idx * 8 < n; idx += stride) {
    const float4 a = ((const float4*)in)[idx * 2];
    const float4 b = ((const float4*)in)[idx * 2 + 1];
    bf16x8 v = { (__bf16)a.x, (__bf16)a.y, (__bf16)a.z, (__bf16)a.w,
                 (__bf16)b.x, (__bf16)b.y, (__bf16)b.z, (__bf16)b.w };
    *(bf16x8*)(out + (size_t)idx * 8) = v;
  }
}

// ---------- shared 128x128 GEMM mainloop: acc = A[128,K] * W[128,K]^T ----------
__device__ __forceinline__ void gemm_tile_128(const __bf16* __restrict__ A,
                                              const __bf16* __restrict__ W,
                                              int bm, int bn, int Kd,
                                              f32x4 (&acc)[4][4])
{
  __shared__ __align__(16) __bf16 As[128 * 32];
  __shared__ __align__(16) __bf16 Bs[128 * 32];
  const int tid  = threadIdx.x;
  const int wave = tid >> 6, lane = tid & 63;
  const int wr = wave >> 1, wc = wave & 1;
  const int fr = lane & 15, fq = lane >> 4;
  const int c0 = tid, c1 = tid + 256;
  const __bf16* gA0 = A + (size_t)(bm * 128 + (c0 >> 2)) * Kd + (c0 & 3) * 8;
  const __bf16* gA1 = A + (size_t)(bm * 128 + (c1 >> 2)) * Kd + (c1 & 3) * 8;
  const __bf16* gB0 = W + (size_t)(bn * 128 + (c0 >> 2)) * Kd + (c0 & 3) * 8;
  const __bf16* gB1 = W + (size_t)(bn * 128 + (c1 >> 2)) * Kd + (c1 & 3) * 8;

  for (int k0 = 0; k0 < Kd; k0 += 32) {
    gload_lds16(gA0 + k0, As + c0 * 8);
    gload_lds16(gB0 + k0, Bs + c0 * 8);
    gload_lds16(gA1 + k0, As + c1 * 8);
    gload_lds16(gB1 + k0, Bs + c1 * 8);
    __syncthreads();
    bf16x8 a[4], b[4];
#pragma unroll
    for (int m = 0; m < 4; ++m)
      a[m] = *(const bf16x8*)(As + (wr * 64 + m * 16 + fr) * 32 + fq * 8);
#pragma unroll
    for (int n = 0; n < 4; ++n)
      b[n] = *(const bf16x8*)(Bs + (wc * 64 + n * 16 + fr) * 32 + fq * 8);
#pragma unroll
    for (int m = 0; m < 4; ++m)
#pragma unroll
      for (int n = 0; n < 4; ++n)
        acc[m][n] = __builtin_amdgcn_mfma_f32_16x16x32_bf16(a[m], b[n], acc[m][n], 0, 0, 0);
    __syncthreads();
  }
}

// ---------- QKV projections ----------
// z=0: Q (row-major, *qscale). z=1: K packed fragment-order. z=2: V packed
// fragment-order (computed as VT = Wv * x^T).
// PK layout: [b][h][t32=64][kc=4][lane=64][j=8]   (256KB per (b,h))
// PV layout: [b][h][t64=32][db=2][kc=4][lane=64][j=8]
__global__ __launch_bounds__(256)
void gemm_qkv(const __bf16* __restrict__ xb,
              const __bf16* __restrict__ Wq, const __bf16* __restrict__ Wk,
              const __bf16* __restrict__ Wv,
              __bf16* __restrict__ Qo, __bf16* __restrict__ Ko, __bf16* __restrict__ VTo,
              float qscale)
{
  const int z = blockIdx.z;
  const __bf16* A; const __bf16* W; __bf16* Ob; int bm, bn;
  if (z == 2)      { A = Wv; W = xb; Ob = VTo; bm = blockIdx.y; bn = blockIdx.x; }
  else if (z == 1) { A = xb; W = Wk; Ob = Ko;  bm = blockIdx.x; bn = blockIdx.y; }
  else             { A = xb; W = Wq; Ob = Qo;  bm = blockIdx.x; bn = blockIdx.y; }

  f32x4 acc[4][4] = {};
  gemm_tile_128(A, W, bm, bn, DMODEL, acc);

  const int lane = threadIdx.x & 63, wave = threadIdx.x >> 6;
  const int wr = wave >> 1, wc = wave & 1;
  const int fr = lane & 15, fq = lane >> 4;

  if (z == 0) {
#pragma unroll
    for (int m = 0; m < 4; ++m)
#pragma unroll
      for (int n = 0; n < 4; ++n) {
        const int col = bn * 128 + wc * 64 + n * 16 + fr;
#pragma unroll
        for (int j = 0; j < 4; ++j) {
          const int row = bm * 128 + wr * 64 + m * 16 + fq * 4 + j;
          Ob[(size_t)row * DMODEL + col] = (__bf16)(acc[m][n][j] * qscale);
        }
      }
  } else if (z == 1) {
    // K packed: row = token, col = feature
#pragma unroll
    for (int m = 0; m < 4; ++m)
#pragma unroll
      for (int n = 0; n < 4; ++n) {
        const int f = bn * 128 + wc * 64 + n * 16 + fr;
        const int h = f >> 6;
        const int kc = (f >> 4) & 3, hi = (f >> 3) & 1, jj = f & 7;
#pragma unroll
        for (int j = 0; j < 4; ++j) {
          const int tkn = bm * 128 + wr * 64 + m * 16 + fq * 4 + j;
          const int bb = tkn >> 11, n2 = tkn & 2047;
          const int t32 = n2 >> 5, ln2 = n2 & 31;
          const size_t idx = (((((size_t)bb * 16 + h) * 64 + t32) * 4 + kc) * 64
                              + (ln2 + (hi << 5))) * 8 + jj;
          Ob[idx] = (__bf16)acc[m][n][j];
        }
      }
  } else {
    // V packed: row = feature, col = token
#pragma unroll
    for (int m = 0; m < 4; ++m)
#pragma unroll
      for (int n = 0; n < 4; ++n) {
        const int tkn = bn * 128 + wc * 64 + n * 16 + fr;
        const int bb = tkn >> 11, n2 = tkn & 2047;
        const int t64 = n2 >> 6, w2 = n2 & 63;
        const int kc = w2 >> 4, hi = (w2 >> 3) & 1, jj = w2 & 7;
#pragma unroll
        for (int j = 0; j < 4; ++j) {
          const int f = bm * 128 + wr * 64 + m * 16 + fq * 4 + j;
          const int h = f >> 6, d = f & 63;
          const int db = d >> 5, ln2 = d & 31;
          const size_t idx = ((((((size_t)bb * 16 + h) * 32 + t64) * 2 + db) * 4 + kc) * 64
                              + (ln2 + (hi << 5))) * 8 + jj;
          Ob[idx] = (__bf16)acc[m][n][j];
        }
      }
  }
}

// ---------- output projection: out = ctx * Wo^T + b ----------
__global__ __launch_bounds__(256)
void gemm_out(const __bf16* __restrict__ A, const __bf16* __restrict__ W,
              float* __restrict__ OF, const float* __restrict__ bias)
{
  f32x4 acc[4][4] = {};
  gemm_tile_128(A, W, blockIdx.x, blockIdx.y, DMODEL, acc);

  const int lane = threadIdx.x & 63, wave = threadIdx.x >> 6;
  const int wr = wave >> 1, wc = wave & 1;
  const int fr = lane & 15, fq = lane >> 4;
#pragma unroll
  for (int m = 0; m < 4; ++m)
#pragma unroll
    for (int n = 0; n < 4; ++n) {
      const int col = blockIdx.y * 128 + wc * 64 + n * 16 + fr;
#pragma unroll
      for (int j = 0; j < 4; ++j) {
        const int row = blockIdx.x * 128 + wr * 64 + m * 16 + fq * 4 + j;
        OF[(size_t)row * DMODEL + col] = acc[m][n][j] + bias[col];
      }
    }
}

// ---------- flash attention (round-5 structure + packed K/V streams) ----------
// WG = 128 thr = 2 waves. Both waves own q-tile pair (jp, 63-jp); kv tiles
// split by parity. Fixed-offset softmax (P = exp2(S-8), offset cancels in
// normalization) -> parity partials combine additively via LDS + 1 barrier.
// All K/V inner-loop loads are consecutive-lane-consecutive-16B (packed
// fragment order) -> single coalesced transaction per instruction.
// Swapped QK^T via 32x32x16 MFMA: S^T[kv][q], q = lane&31.
// C/D layout (m74/m101): col=lane&31, row=(r&3)+8*(r>>2)+4*(lane>>5).

__device__ __forceinline__ void mask_tile(f32x16& sv0, f32x16& sv1,
                                          int kv0, int q0, int ln, int hi)
{
  const int qg = q0 + ln;
#pragma unroll
  for (int r = 0; r < 16; ++r) {
    const int kvo = kv0 + (r & 3) + 8 * (r >> 2) + 4 * hi;
    if (kvo > qg)      sv0[r] = -1e30f;
    if (kvo + 32 > qg) sv1[r] = -1e30f;
  }
}

// exp2(S - MOFF), lane-local l accumulate, pack P, PV accumulate
__device__ __forceinline__ void stream_fin(f32x16& sv0, f32x16& sv1, float& l_acc,
                                           f32x16& c0, f32x16& c1,
                                           const bf16x8 (&vt0)[4], const bf16x8 (&vt1)[4],
                                           int hi)
{
#pragma unroll
  for (int r = 0; r < 16; ++r) {
    sv0[r] = __builtin_amdgcn_exp2f(sv0[r] - MOFF);
    sv1[r] = __builtin_amdgcn_exp2f(sv1[r] - MOFF);
  }
  float s8[8];
#pragma unroll
  for (int r = 0; r < 8; ++r)
    s8[r] = (sv0[r] + sv0[r + 8]) + (sv1[r] + sv1[r + 8]);
#pragma unroll
  for (int r = 0; r < 4; ++r) s8[r] += s8[r + 4];
  l_acc += (s8[0] + s8[1]) + (s8[2] + s8[3]);

  // pack P into PV B-fragments (half-exchange via shfl_xor 32)
  bf16x8 pf[4];
#pragma unroll
  for (int half = 0; half < 2; ++half) {
    const int r0 = half * 8;
    {
      unsigned pk01 = pkbf(sv0[r0 + 0], sv0[r0 + 1]);
      unsigned pk23 = pkbf(sv0[r0 + 2], sv0[r0 + 3]);
      unsigned pk45 = pkbf(sv0[r0 + 4], sv0[r0 + 5]);
      unsigned pk67 = pkbf(sv0[r0 + 6], sv0[r0 + 7]);
      unsigned x01 = (unsigned)__shfl_xor((int)pk01, 32, 64);
      unsigned x23 = (unsigned)__shfl_xor((int)pk23, 32, 64);
      unsigned x45 = (unsigned)__shfl_xor((int)pk45, 32, 64);
      unsigned x67 = (unsigned)__shfl_xor((int)pk67, 32, 64);
      u32x4 uw = { hi ? x45 : pk01, hi ? x67 : pk23,
                   hi ? pk45 : x01, hi ? pk67 : x23 };
      pf[half] = __builtin_bit_cast(bf16x8, uw);
    }
    {
      unsigned pk01 = pkbf(sv1[r0 + 0], sv1[r0 + 1]);
      unsigned pk23 = pkbf(sv1[r0 + 2], sv1[r0 + 3]);
      unsigned pk45 = pkbf(sv1[r0 + 4], sv1[r0 + 5]);
      unsigned pk67 = pkbf(sv1[r0 + 6], sv1[r0 + 7]);
      unsigned x01 = (unsigned)__shfl_xor((int)pk01, 32, 64);
      unsigned x23 = (unsigned)__shfl_xor((int)pk23, 32, 64);
      unsigned x45 = (unsigned)__shfl_xor((int)pk45, 32, 64);
      unsigned x67 = (unsigned)__shfl_xor((int)pk67, 32, 64);
      u32x4 uw = { hi ? x45 : pk01, hi ? x67 : pk23,
                   hi ? pk45 : x01, hi ? pk67 : x23 };
      pf[2 + half] = __builtin_bit_cast(bf16x8, uw);
    }
  }

  // PV: ctx^T[d][q] += V^T-frag * P-frag
  __builtin_amdgcn_s_setprio(1);
#pragma unroll
  for (int kc = 0; kc < 4; ++kc)
    c0 = __builtin_amdgcn_mfma_f32_32x32x16_bf16(vt0[kc], pf[kc], c0, 0, 0, 0);
#pragma unroll
  for (int kc = 0; kc < 4; ++kc)
    c1 = __builtin_amdgcn_mfma_f32_32x32x16_bf16(vt1[kc], pf[kc], c1, 0, 0, 0);
  __builtin_amdgcn_s_setprio(0);
}

__global__ __launch_bounds__(128, 2)
void attn_kernel(const __bf16* __restrict__ Qg, const __bf16* __restrict__ PK,
                 const __bf16* __restrict__ PV, __bf16* __restrict__ Og)
{
  __shared__ __align__(16) float Cs[2][32][68];   // [exported stream][q][d+pad]
  __shared__ float Ls[2][2][32];                  // [exported stream][hi][q]

  const int tid  = threadIdx.x;
  const int p    = tid >> 6;          // wave id = kv parity
  const int lane = tid & 63;
  const int ln = lane & 31, hi = lane >> 5;
  const int bI = blockIdx.x;          // 0..1023
  const int bh = bI & 31;             // bh%8 == blockIdx%8 -> XCD L2 locality
  const int jp = bI >> 5;             // 0..31 -> q-tile pair (jp, 63-jp)
  const int b = bh >> 4, h = bh & 15;

  const int qtL = jp, qtH = 63 - jp;
  const int q0L = qtL * 32, q0H = qtH * 32;
  const int ntL = (qtL >> 1) + 1, ntH = (qtH >> 1) + 1;   // ntL <= ntH

  // packed per-(b,h) bases: 131072 elems each
  const __bf16* Kp  = PK + (size_t)(b * 16 + h) * (64 * 4 * 64 * 8);
  const __bf16* Vp  = PV + (size_t)(b * 16 + h) * (32 * 2 * 4 * 64 * 8);
  const __bf16* QpL = Qg + ((size_t)b * SEQ + q0L + ln) * DMODEL + h * HDIM + hi * 8;
  const __bf16* QpH = Qg + ((size_t)b * SEQ + q0H + ln) * DMODEL + h * HDIM + hi * 8;

  // Q fragments (B-operand): q=ln, k = kc*16 + hi*8 + j  (Q pre-scaled 0.125*log2e)
  bf16x8 qfL[4], qfH[4];
#pragma unroll
  for (int kc = 0; kc < 4; ++kc) {
    qfL[kc] = *(const bf16x8*)(QpL + kc * 16);
    qfH[kc] = *(const bf16x8*)(QpH + kc * 16);
  }

  f32x16 cL0 = {}, cL1 = {}, cH0 = {}, cH1 = {};
  float lL = 0.f, lH = 0.f;

  for (int t = p; t < ntH; t += 2) {
    // packed tile bases: 4096 elems (8KB) per 64-kv tile, fully linear
    const __bf16* kt = Kp + (size_t)t * 4096;
    const __bf16* vt = Vp + (size_t)t * 4096;

    bf16x8 kA[4], kB[4], vt0[4], vt1[4];
#pragma unroll
    for (int kc = 0; kc < 4; ++kc) {
      kA[kc]  = *(const bf16x8*)(kt + (kc * 64 + lane) * 8);
      kB[kc]  = *(const bf16x8*)(kt + 2048 + (kc * 64 + lane) * 8);
    }
#pragma unroll
    for (int kc = 0; kc < 4; ++kc) {
      vt0[kc] = *(const bf16x8*)(vt + (kc * 64 + lane) * 8);
      vt1[kc] = *(const bf16x8*)(vt + 2048 + (kc * 64 + lane) * 8);
    }

    const int kv0 = t * 64;

    // ---- H stream (always active) ----
    {
      f32x16 s0 = {}, s1 = {};
      __builtin_amdgcn_s_setprio(1);
#pragma unroll
      for (int kc = 0; kc < 4; ++kc) {
        s0 = __builtin_amdgcn_mfma_f32_32x32x16_bf16(kA[kc], qfH[kc], s0, 0, 0, 0);
        s1 = __builtin_amdgcn_mfma_f32_32x32x16_bf16(kB[kc], qfH[kc], s1, 0, 0, 0);
      }
      __builtin_amdgcn_s_setprio(0);
      if (t == ntH - 1) mask_tile(s0, s1, kv0, q0H, ln, hi);
      stream_fin(s0, s1, lH, cH0, cH1, vt0, vt1, hi);
    }

    // ---- L stream (while active) ----
    if (t < ntL) {
      f32x16 s0 = {}, s1 = {};
      __builtin_amdgcn_s_setprio(1);
#pragma unroll
      for (int kc = 0; kc < 4; ++kc) {
        s0 = __builtin_amdgcn_mfma_f32_32x32x16_bf16(kA[kc], qfL[kc], s0, 0, 0, 0);
        s1 = __builtin_amdgcn_mfma_f32_32x32x16_bf16(kB[kc], qfL[kc], s1, 0, 0, 0);
      }
      __builtin_amdgcn_s_setprio(0);
      if (t == ntL - 1) mask_tile(s0, s1, kv0, q0L, ln, hi);
      stream_fin(s0, s1, lL, cL0, cL1, vt0, vt1, hi);
    }
  }

  // ---- cross-wave combine: wave0 exports its H partial, wave1 its L partial ----
  if (p == 0) {
#pragma unroll
    for (int g = 0; g < 4; ++g) {
      f32x4 v0 = { cH0[4*g+0], cH0[4*g+1], cH0[4*g+2], cH0[4*g+3] };
      f32x4 v1 = { cH1[4*g+0], cH1[4*g+1], cH1[4*g+2], cH1[4*g+3] };
      *(f32x4*)&Cs[1][ln][g * 8 + hi * 4]      = v0;
      *(f32x4*)&Cs[1][ln][32 + g * 8 + hi * 4] = v1;
    }
    Ls[1][hi][ln] = lH;
  } else {
#pragma unroll
    for (int g = 0; g < 4; ++g) {
      f32x4 v0 = { cL0[4*g+0], cL0[4*g+1], cL0[4*g+2], cL0[4*g+3] };
      f32x4 v1 = { cL1[4*g+0], cL1[4*g+1], cL1[4*g+2], cL1[4*g+3] };
      *(f32x4*)&Cs[0][ln][g * 8 + hi * 4]      = v0;
      *(f32x4*)&Cs[0][ln][32 + g * 8 + hi * 4] = v1;
    }
    Ls[0][hi][ln] = lL;
  }
  __syncthreads();

  if (p == 0) {
    // finish L stream: own parity-0 partial + wave1's parity-1 partial
    const float lt = lL + __shfl_xor(lL, 32, 64) + Ls[0][0][ln] + Ls[0][1][ln];
    const float inv = 1.0f / lt;
    __bf16* Op = Og + ((size_t)b * SEQ + q0L + ln) * DMODEL + h * HDIM;
#pragma unroll
    for (int g = 0; g < 4; ++g) {
      const f32x4 u0 = *(const f32x4*)&Cs[0][ln][g * 8 + hi * 4];
      const f32x4 u1 = *(const f32x4*)&Cs[0][ln][32 + g * 8 + hi * 4];
      u32x2 w;
      w.x = pkbf((cL0[4*g+0] + u0[0]) * inv, (cL0[4*g+1] + u0[1]) * inv);
      w.y = pkbf((cL0[4*g+2] + u0[2]) * inv, (cL0[4*g+3] + u0[3]) * inv);
      *(u32x2*)(Op + g * 8 + hi * 4) = w;
      w.x = pkbf((cL1[4*g+0] + u1[0]) * inv, (cL1[4*g+1] + u1[1]) * inv);
      w.y = pkbf((cL1[4*g+2] + u1[2]) * inv, (cL1[4*g+3] + u1[3]) * inv);
      *(u32x2*)(Op + 32 + g * 8 + hi * 4) = w;
    }
  } else {
    // finish H stream: own parity-1 partial + wave0's parity-0 partial
    const float lt = lH + __shfl_xor(lH, 32, 64) + Ls[1][0][ln] + Ls[1][1][ln];
    const float inv = 1.0f / lt;
    __bf16* Op = Og + ((size_t)b * SEQ + q0H + ln) * DMODEL + h * HDIM;
#pragma unroll
    for (int g = 0; g < 4; ++g) {
      const f32x4 u0 = *(const f32x4*)&Cs[1][ln][g * 8 + hi * 4];
      const f32x4 u1 = *(const f32x4*)&Cs[1][ln][32 + g * 8 + hi * 4];
      u32x2 w;
      w.x = pkbf((cH0[4*g+0] + u0[0]) * inv, (cH0[4*g+1] + u0[1]) * inv);
      w.y = pkbf((cH0[4*g+2] + u0[2]) * inv, (cH0[4*g+3] + u0[3]) * inv);
      *(u32x2*)(Op + g * 8 + hi * 4) = w;
      w.x = pkbf((cH1[4*g+0] + u1[0]) * inv, (cH1[4*g+1] + u1[1]) * inv);
      w.y = pkbf((cH1[4*g+2] + u1[2]) * inv, (cH1[4*g+3] + u1[3]) * inv);
      *(u32x2*)(Op + 32 + g * 8 + hi * 4) = w;
    }
  }
}

// ---------- launch ----------
extern "C" void kernel_launch(void* const* d_in, const int* in_sizes, int n_in,
                              void* d_out, int out_size, void* d_ws, size_t ws_size,
                              hipStream_t stream) {
  (void)in_sizes; (void)n_in; (void)out_size; (void)ws_size;
  const float* x  = (const float*)d_in[0];
  const float* Wq = (const float*)d_in[1];
  const float* Wk = (const float*)d_in[2];
  const float* Wv = (const float*)d_in[3];
  const float* Wo = (const float*)d_in[4];
  const float* bo = (const float*)d_in[5];
  float* out = (float*)d_out;

  __bf16* ws  = (__bf16*)d_ws;
  __bf16* xb  = ws;                                   // 4M elems
  __bf16* Wqb = xb  + (size_t)MTOT * DMODEL;
  __bf16* Wkb = Wqb + (size_t)DMODEL * DMODEL;
  __bf16* Wvb = Wkb + (size_t)DMODEL * DMODEL;
  __bf16* Wob = Wvb + (size_t)DMODEL * DMODEL;
  __bf16* Qb  = Wob + (size_t)DMODEL * DMODEL;        // 4M
  __bf16* Kpk = Qb  + (size_t)MTOT * DMODEL;          // 4M, packed fragment order
  __bf16* Vpk = Kpk + (size_t)MTOT * DMODEL;          // 4M, packed fragment order
  __bf16* ctxb = xb;  // reuse: x is dead after QKV projections

  cast_all<<<dim3(256, 5), 256, 0, stream>>>(x, Wq, Wk, Wv, Wo,
                                             xb, Wqb, Wkb, Wvb, Wob);

  // scale = 1/sqrt(64) * log2(e), folded into Q so softmax uses exp2
  const float qscale = 0.125f * 1.4426950408889634f;
  gemm_qkv<<<dim3(32, 8, 3), 256, 0, stream>>>(xb, Wqb, Wkb, Wvb, Qb, Kpk, Vpk, qscale);

  attn_kernel<<<dim3(1024), 128, 0, stream>>>(Qb, Kpk, Vpk, ctxb);

  gemm_out<<<dim3(32, 8), 256, 0, stream>>>(ctxb, Wob, out, bo);
}